// Round 6
// baseline (73.466 us; speedup 1.0000x reference)
//
#include <hip/hip_runtime.h>
#include <math.h>

#define NIMG 64
#define HW   1024
#define NCH  85
#define NCLS 80
#define CONF_TH 0.25f
#define NMS_TH  0.35f

__device__ __forceinline__ float fast_tanh(float x) {
  float e = __expf(2.0f * x);
  return 1.0f - 2.0f * __builtin_amdgcn_rcpf(e + 1.0f);
}
__device__ __forceinline__ float fast_sigmoid(float x) {
  return __builtin_amdgcn_rcpf(1.0f + __expf(-x));
}

// Partial argmax over NC class channels starting at absolute channel CL0,
// for 4 consecutive pixels (float4 lanes). Ascending channel order + strict >
// == exact first-occurrence argmax within the quarter.
template <int CL0, int NC>
__device__ __forceinline__ void quarter_argmax(const float* __restrict__ bp,
                                               float4& mv, int4& mi) {
  float4 v = *(const float4*)(bp + (size_t)CL0 * HW);
  float b0 = v.x, b1 = v.y, b2 = v.z, b3 = v.w;
  int i0 = CL0 - 5, i1 = i0, i2 = i0, i3 = i0;
#pragma unroll
  for (int c = 1; c < NC; ++c) {
    float4 u = *(const float4*)(bp + (size_t)(CL0 + c) * HW);
    int ci = CL0 - 5 + c;
    if (u.x > b0) { b0 = u.x; i0 = ci; }
    if (u.y > b1) { b1 = u.y; i1 = ci; }
    if (u.z > b2) { b2 = u.z; i2 = ci; }
    if (u.w > b3) { b3 = u.w; i3 = ci; }
  }
  mv = make_float4(b0, b1, b2, b3);
  mi = make_int4(i0, i1, i2, i3);
}

// ---------------------------------------------------------------------------
// Fused decode + class-aware NMS. One block per image, 1024 threads.
// Decode: float4 loads (1 KB/wave-instr), channel space split across 4
// wave-uniform thread quarters; partials combined per-pixel via LDS.
// NMS: parallel rank + parallel suppression bitmasks + O(m) serial bit-scan,
// final keep mask written once, fully coalesced.
// ---------------------------------------------------------------------------
__global__ __launch_bounds__(1024) void fused_kernel(const float* __restrict__ preds,
                                                     float* __restrict__ out,
                                                     float* __restrict__ keepOut) {
  int n = blockIdx.x;
  int t = threadIdx.x;
  int q  = t >> 8;          // channel quarter (wave-uniform)
  int pg = t & 255;         // pixel group: pixels 4*pg .. 4*pg+3

  __shared__ float sx1[HW], sy1[HW], sx2[HW], sy2[HW], sarea[HW], sscore[HW];
  __shared__ int bucket[HW];                 // unordered class members
  __shared__ int sorted[HW];                 // (score desc, idx asc) order
  __shared__ int srank[HW];
  __shared__ unsigned long long supp[HW];    // suppression bits vs lower ranks
  __shared__ unsigned char skeep[HW];        // final keep flag per pixel
  __shared__ int cnt[NCLS], offs[NCLS], start[NCLS];
  __shared__ float pmaxv[4][HW];             // per-quarter partial max  [q][pixel]
  __shared__ int   pmaxi[4][HW];             // per-quarter partial argmax
  __shared__ float sobj[HW];
  __shared__ float sreg[4][HW];              // tx, ty, tw, th

  if (t < NCLS) cnt[t] = 0;
  skeep[t] = 0;

  // ---- decode phase A: cooperative float4 channel loads ----
  const float* bp = preds + (size_t)n * (NCH * HW) + 4 * pg;
  float4 mv; int4 mi;
  if (q == 0) {
    float4 vobj = *(const float4*)(bp);
    ((float4*)sobj)[pg] = vobj;
#pragma unroll
    for (int r = 0; r < 4; ++r) {
      float4 vr = *(const float4*)(bp + (size_t)(1 + r) * HW);
      ((float4*)&sreg[r][0])[pg] = vr;
    }
    quarter_argmax<5, 16>(bp, mv, mi);     // classes  0..15
  } else if (q == 1) {
    quarter_argmax<21, 21>(bp, mv, mi);    // classes 16..36
  } else if (q == 2) {
    quarter_argmax<42, 21>(bp, mv, mi);    // classes 37..57
  } else {
    quarter_argmax<63, 22>(bp, mv, mi);    // classes 58..79
  }
  ((float4*)&pmaxv[q][0])[pg] = mv;
  ((int4*)&pmaxi[q][0])[pg] = mi;
  __syncthreads();

  // ---- decode phase B: per-pixel combine (ascending q, strict > ==
  //      exact first-occurrence across quarters) + box math ----
  float pobj = sobj[t];
  float tx = sreg[0][t], ty = sreg[1][t], tw = sreg[2][t], th = sreg[3][t];
  float best = pmaxv[0][t]; int bc = pmaxi[0][t];
#pragma unroll
  for (int qq = 1; qq < 4; ++qq) {
    float v = pmaxv[qq][t];
    if (v > best) { best = v; bc = pmaxi[qq][t]; }
  }
  float score = pobj * best;               // bit-exact vs reference

  float gx = (float)(t & 31);
  float gy = (float)(t >> 5);
  float bcx = (fast_tanh(tx) + gx) * 0.03125f;
  float bcy = (fast_tanh(ty) + gy) * 0.03125f;
  float bw = fast_sigmoid(tw);
  float bh = fast_sigmoid(th);

  float x1 = bcx - 0.5f * bw, y1 = bcy - 0.5f * bh;
  float x2 = bcx + 0.5f * bw, y2 = bcy + 0.5f * bh;

  size_t gb = (size_t)n * HW + t;
  float2* ob = (float2*)(out + gb * 6);    // fire-and-forget output store
  ob[0] = make_float2(x1, y1);
  ob[1] = make_float2(x2, y2);
  ob[2] = make_float2(score, (float)bc);

  sx1[t] = x1; sy1[t] = y1; sx2[t] = x2; sy2[t] = y2;
  float aar = (x2 - x1) * (y2 - y1);
  sarea[t] = aar;
  sscore[t] = score;
  bool valid = score > CONF_TH;
  __syncthreads();

  // ---- count valid per class ----
  if (valid) atomicAdd(&cnt[bc], 1);
  __syncthreads();

  // ---- exclusive prefix sum over 80 class counts (wave-0 shfl scan) ----
  if (t < 64) {
    int c0 = (2 * t < NCLS) ? cnt[2 * t] : 0;
    int c1 = (2 * t + 1 < NCLS) ? cnt[2 * t + 1] : 0;
    int ps = c0 + c1;
    int x = ps;
#pragma unroll
    for (int d = 1; d < 64; d <<= 1) {
      int y = __shfl_up(x, d, 64);
      if (t >= d) x += y;
    }
    int excl = x - ps;
    if (2 * t < NCLS)     { start[2 * t] = excl;          offs[2 * t] = excl; }
    if (2 * t + 1 < NCLS) { start[2 * t + 1] = excl + c0; offs[2 * t + 1] = excl + c0; }
  }
  __syncthreads();

  // ---- scatter valid boxes to class buckets (order irrelevant) ----
  if (valid) {
    int p = atomicAdd(&offs[bc], 1);
    bucket[p] = t;
  }
  __syncthreads();

  // ---- parallel rank within class = exact stable-argsort position ----
  if (valid) {
    int s0 = start[bc], m = cnt[bc];
    int r = 0;
    for (int j = 0; j < m; ++j) {
      int jb = bucket[s0 + j];
      float sj = sscore[jb];
      r += (sj > score) || (sj == score && jb < t);
    }
    srank[t] = r;
    sorted[s0 + r] = t;
  }
  __syncthreads();

  // ---- parallel suppression bitmasks vs all lower-rank members ----
  if (valid) {
    int s0 = start[bc];
    int a = srank[t];
    int lim = a < 64 ? a : 64;
    unsigned long long mask = 0ull;
    for (int b = 0; b < lim; ++b) {
      int jb = sorted[s0 + b];
      float iw = fminf(x2, sx2[jb]) - fmaxf(x1, sx1[jb]);
      float ih = fminf(y2, sy2[jb]) - fmaxf(y1, sy1[jb]);
      iw = fmaxf(iw, 0.0f);
      ih = fmaxf(ih, 0.0f);
      float inter = iw * ih;
      float iou = inter / (aar + sarea[jb] - inter + 1e-9f);  // exact ref op order
      if (iou > NMS_TH) mask |= (1ull << b);
    }
    supp[s0 + a] = mask;
  }
  __syncthreads();

  // ---- serial greedy scan per class: O(m) register bit-ops ----
  if (t < NCLS) {
    int m = cnt[t], s0 = start[t];
    if (m <= 64) {
      unsigned long long kept = 0ull;
      for (int a = 0; a < m; ++a) {
        unsigned long long sa = supp[s0 + a];
        if ((sa & kept) == 0ull) {
          kept |= (1ull << a);
          skeep[sorted[s0 + a]] = 1;
        }
      }
    } else {
      // never expected (Poisson mean ~6/class); exact O(m^2) fallback
      for (int a = 0; a < m; ++a) {
        int ia = sorted[s0 + a];
        float ax1 = sx1[ia], ay1 = sy1[ia], ax2 = sx2[ia], ay2 = sy2[ia];
        float ar2 = sarea[ia];
        bool kp = true;
        for (int b = 0; b < a; ++b) {
          if (!bucket[s0 + b]) continue;   // bucket reused as kept-flags
          int jb = sorted[s0 + b];
          float iw = fminf(ax2, sx2[jb]) - fmaxf(ax1, sx1[jb]);
          float ih = fminf(ay2, sy2[jb]) - fmaxf(ay1, sy1[jb]);
          iw = fmaxf(iw, 0.0f);
          ih = fmaxf(ih, 0.0f);
          float inter = iw * ih;
          float iou = inter / (ar2 + sarea[jb] - inter + 1e-9f);
          if (iou > NMS_TH) { kp = false; break; }
        }
        bucket[s0 + a] = kp ? 1 : 0;
        if (kp) skeep[ia] = 1;
      }
    }
  }
  __syncthreads();

  // ---- single fully-coalesced keep store ----
  keepOut[gb] = (float)skeep[t];
}

extern "C" void kernel_launch(void* const* d_in, const int* in_sizes, int n_in,
                              void* d_out, int out_size, void* d_ws, size_t ws_size,
                              hipStream_t stream) {
  const float* preds = (const float*)d_in[0];
  float* out = (float*)d_out;
  float* keepOut = out + (size_t)NIMG * HW * 6;

  fused_kernel<<<NIMG, HW, 0, stream>>>(preds, out, keepOut);
}